// Round 7
// baseline (534.554 us; speedup 1.0000x reference)
//
#include <hip/hip_runtime.h>
#include <hip/hip_bf16.h>

#define NN 2048
#define NB 16
#define CAT_PITCH 136    // shorts per cat/out row (272 B == 68 words == 4 mod 32)
#define XT_OFF 16384     // byte offset of xt/red/cat region (phs/ehs below persist)
#define SMEM_BYTES 147456

typedef __attribute__((ext_vector_type(8))) short short8;
typedef __attribute__((ext_vector_type(4))) float f32x4;

static __device__ __forceinline__ float bfbits2f(short s) {
  unsigned int u = ((unsigned int)(unsigned short)s) << 16;
  float f; __builtin_memcpy(&f, &u, 4); return f;
}
static __device__ __forceinline__ short f2bfbits(float f) {
  __hip_bfloat16 h = __float2bfloat16(f);
  unsigned short us; __builtin_memcpy(&us, &h, 2); return (short)us;
}
static __device__ __forceinline__ float exp2_fast(float x) {
#if __has_builtin(__builtin_amdgcn_exp2f)
  return __builtin_amdgcn_exp2f(x);
#else
  return exp2f(x);
#endif
}
// pack two f32 -> two bf16 (round-half-up) in one v_perm
static __device__ __forceinline__ unsigned pack2bf(float f0, float f1) {
  unsigned u0, u1;
  __builtin_memcpy(&u0, &f0, 4);
  __builtin_memcpy(&u1, &f1, 4);
  return __builtin_amdgcn_perm(u1 + 0x8000u, u0 + 0x8000u, 0x07060302u);
}
// async global->LDS, 16B per lane, wave-uniform LDS base + lane*16
static __device__ __forceinline__ void gload_lds16(const void* g, void* l) {
  __builtin_amdgcn_global_load_lds(
      (const __attribute__((address_space(1))) unsigned int*)g,
      (__attribute__((address_space(3))) unsigned int*)l, 16, 0, 0);
}

// ---------------------------------------------------------------------------
// Device-scope grid barrier (sense-reversal). All 256 blocks are co-resident
// (144 KB LDS -> 1 block/CU, grid == 256 == CU count). Bounded spin: a
// pathological straggler fails correctness instead of hanging the queue.
// ---------------------------------------------------------------------------
static __device__ __forceinline__ void grid_barrier(unsigned* bar, unsigned nb) {
  __syncthreads();
  if (threadIdx.x == 0) {
    __threadfence();  // agent-scope release of this block's prior stores
    unsigned gen = __hip_atomic_load(&bar[1], __ATOMIC_RELAXED, __HIP_MEMORY_SCOPE_AGENT);
    unsigned arr = __hip_atomic_fetch_add(&bar[0], 1u, __ATOMIC_ACQ_REL, __HIP_MEMORY_SCOPE_AGENT);
    if (arr == nb - 1u) {
      __hip_atomic_store(&bar[0], 0u, __ATOMIC_RELAXED, __HIP_MEMORY_SCOPE_AGENT);
      __hip_atomic_store(&bar[1], gen + 1u, __ATOMIC_RELEASE, __HIP_MEMORY_SCOPE_AGENT);
    } else {
      long cnt = 0;
      while (__hip_atomic_load(&bar[1], __ATOMIC_ACQUIRE, __HIP_MEMORY_SCOPE_AGENT) == gen) {
        __builtin_amdgcn_s_sleep(8);
        if (++cnt > (1L << 22)) break;  // ~<1s worst case: fail, don't hang
      }
    }
  }
  __syncthreads();
}

struct Params {
  const float *e, *phi, *eta;
  const float *W0, *W1, *W2, *W3;     // layer weights [cout, 2*cin]
  const float *B0, *B1, *B2, *B3;     // bias
  const float *R0, *R1, *R2, *R3;     // Wr
  const float *Q0, *Q1, *Q2, *Q3;     // br
  const float *fcW, *fcb;
  float* out;
  short *xA, *xB;   // bf16 activations [B][64][NN]
  short* blob;      // packed weights, 25088 shorts (50176 B) per layer
  unsigned* bar;
};

// ---------------------------------------------------------------------------
// Stage one 64-j chunk for all 8 j-groups via global_load_lds with
// pre-swizzled global source (LDS dest linear; verified round 5).
// ---------------------------------------------------------------------------
static __device__ __forceinline__ void stage_chunk(
    const short* __restrict__ xb, char* smem, int wave, int lane, int tt) {
  const int par = tt & 1;
#pragma unroll
  for (int q = 0; q < 4; ++q) {
    const int s = wave * 4 + q;   // span 0..63 (1 KB each)
    const int jgs = s >> 3;       // j-group buffer
    const int sl = s & 7;         // 8-ch span within buffer
    const int ch = sl * 8 + (lane >> 3);
    const int jc8 = (lane & 7) ^ (ch & 7);
    const short* g = xb + (size_t)ch * NN + jgs * 256 + tt * 64 + jc8 * 8;
    char* l = smem + XT_OFF + jgs * 16384 + par * 8192 + sl * 1024;  // wave-uniform
    gload_lds16(g, l);
  }
}

// ---------------------------------------------------------------------------
// Whole network in one persistent kernel.
// Block bid -> (batch b = bid>>4, row-block iblk = bid&15, rows i0..i0+128).
// Phase 0: phs/ehs load (persist), bn -> xA, weight prep (blocks 0-3).
// Phases 1-4: fused resgconv layers (round-5 body), barrier between.
// Phase 5: final pooled FC (blocks with iblk==0).
// ---------------------------------------------------------------------------
__global__ __launch_bounds__(1024, 4) void fused_kernel(Params p) {
  const int bid = blockIdx.x;
  const int b = bid >> 4;
  const int iblk = bid & 15;
  const int i0 = iblk * 128;
  const int tid = threadIdx.x;
  const int wave = tid >> 6;
  const int lane = tid & 63;
  const int c0 = lane & 15;
  const int hh = lane >> 4;
  const int koff = hh * 8;
  const int rh = wave & 1;      // row half (64 rows)
  const int jg = wave >> 1;     // j-group (256 j)
  const unsigned nb = gridDim.x;

  __shared__ __align__(16) char smem[SMEM_BYTES];
  float* phs = (float*)smem;          // [2048], persists all layers
  float* ehs = phs + NN;              // [2048]

  // ---------------- phase 0: phs/ehs + bn + prep ----------------
  const float SC = 1.20112240872f;    // sqrt(log2 e): exp2(-(SC*d)^2)=exp(-d^2)
  {
    const float* pb = p.phi + (size_t)b * NN;
    const float* eb = p.eta + (size_t)b * NN;
    for (int idx = tid; idx < NN; idx += 1024) {
      phs[idx] = pb[idx] * SC;
      ehs[idx] = eb[idx] * SC;
    }
  }
  {
    const float* s0 = p.e + (size_t)b * NN;
    const float* s1 = p.eta + (size_t)b * NN;
    const float* s2 = p.phi + (size_t)b * NN;
    float sm0 = 0.f, sq0 = 0.f, sm1 = 0.f, sq1 = 0.f, sm2 = 0.f, sq2 = 0.f;
    for (int idx = tid; idx < NN; idx += 1024) {
      float v0 = s0[idx], v1 = s1[idx], v2 = s2[idx];
      sm0 += v0; sq0 += v0 * v0;
      sm1 += v1; sq1 += v1 * v1;
      sm2 += v2; sq2 += v2 * v2;
    }
    float* bscr = (float*)(smem + XT_OFF);  // [6][1024]
    bscr[tid] = sm0; bscr[1024 + tid] = sq0;
    bscr[2048 + tid] = sm1; bscr[3072 + tid] = sq1;
    bscr[4096 + tid] = sm2; bscr[5120 + tid] = sq2;
    __syncthreads();
    for (int off = 512; off > 0; off >>= 1) {
      if (tid < off) {
#pragma unroll
        for (int f = 0; f < 6; ++f)
          bscr[f * 1024 + tid] += bscr[f * 1024 + tid + off];
      }
      __syncthreads();
    }
    float m0 = bscr[0] * (1.f / NN), m1 = bscr[2048] * (1.f / NN), m2 = bscr[4096] * (1.f / NN);
    float r0 = 1.f / (sqrtf(fmaxf(bscr[1024] * (1.f / NN) - m0 * m0, 0.f)) + 1e-5f);
    float r1 = 1.f / (sqrtf(fmaxf(bscr[3072] * (1.f / NN) - m1 * m1, 0.f)) + 1e-5f);
    float r2 = 1.f / (sqrtf(fmaxf(bscr[5120] * (1.f / NN) - m2 * m2, 0.f)) + 1e-5f);
    // write x0 slice: ch 0..2 = bn(e/eta/phi), ch 3..63 = 0
    const int ch = tid >> 4, part = tid & 15;
    short8 v = {0, 0, 0, 0, 0, 0, 0, 0};
    if (ch < 3) {
      const float* src = ch == 0 ? s0 : (ch == 1 ? s1 : s2);
      const float mm = ch == 0 ? m0 : (ch == 1 ? m1 : m2);
      const float rr = ch == 0 ? r0 : (ch == 1 ? r1 : r2);
#pragma unroll
      for (int q = 0; q < 8; ++q) v[q] = f2bfbits((src[i0 + part * 8 + q] - mm) * rr);
    }
    *(short8*)&p.xA[((size_t)b * 64 + ch) * NN + i0 + part * 8] = v;
  }
  if (bid < 4) {  // weight prep, one block per layer
    const int l = bid;
    const float* W = l == 0 ? p.W0 : l == 1 ? p.W1 : l == 2 ? p.W2 : p.W3;
    const float* R = l == 0 ? p.R0 : l == 1 ? p.R1 : l == 2 ? p.R2 : p.R3;
    const float* BI = l == 0 ? p.B0 : l == 1 ? p.B1 : l == 2 ? p.B2 : p.B3;
    const float* QI = l == 0 ? p.Q0 : l == 1 ? p.Q1 : l == 2 ? p.Q2 : p.Q3;
    const int CIN = l == 0 ? 3 : 64;
    short* base = p.blob + l * 25088;
    for (int f = tid; f < 8192; f += 1024) {
      int e8 = f & 7, ln = (f >> 3) & 63, ks = (f >> 9) & 3, os = f >> 11;
      int o = os * 16 + (ln & 15);
      int k = ks * 32 + (ln >> 4) * 8 + e8;
      float v = 0.f;
      if (k < 64) { if (k < CIN) v = W[o * 2 * CIN + k]; }
      else { int c = k - 64; if (c < CIN) v = W[o * 2 * CIN + CIN + c]; }
      short hi = f2bfbits(v);
      base[f] = hi;
      base[8192 + f] = f2bfbits(v - bfbits2f(hi));
    }
    for (int f = tid; f < 4096; f += 1024) {
      int e8 = f & 7, ln = (f >> 3) & 63, ks = (f >> 9) & 1, os = f >> 10;
      int o = os * 16 + (ln & 15);
      int k = ks * 32 + (ln >> 4) * 8 + e8;
      float v = (k < CIN) ? R[o * CIN + k] : 0.f;
      short hi = f2bfbits(v);
      base[16384 + f] = hi;
      base[20480 + f] = f2bfbits(v - bfbits2f(hi));
    }
    float* bb = (float*)((char*)base + 49152);
    for (int f = tid; f < 64; f += 1024) { bb[f] = BI[f]; bb[64 + f] = QI[f]; }
  }
  grid_barrier(p.bar, nb);

  // hoisted row coordinates (phs/ehs persist)
  float pi_[4], ei_[4];
#pragma unroll
  for (int mt = 0; mt < 4; ++mt) {
    const int row = i0 + rh * 64 + mt * 16 + c0;
    pi_[mt] = phs[row];
    ei_[mt] = ehs[row];
  }

  // ---------------- phases 1-4: layers ----------------
#pragma unroll 1
  for (int l = 0; l < 4; ++l) {
    const short* xin = (l & 1) ? p.xB : p.xA;
    short* xout = (l & 1) ? p.xA : p.xB;
    const short* blobL = p.blob + l * 25088;
    const short* wcat = blobL;
    const short* wrb = blobL + 16384;
    const float* bias = (const float*)((const char*)blobL + 49152);
    const float* brs = bias + 64;
    const short* xb = xin + (size_t)b * 64 * NN;

    stage_chunk(xb, smem, wave, lane, 0);
    __syncthreads();

    f32x4 acc[4][4];
#pragma unroll
    for (int mt = 0; mt < 4; ++mt)
#pragma unroll
      for (int cs = 0; cs < 4; ++cs) acc[mt][cs] = (f32x4){0.f, 0.f, 0.f, 0.f};

    for (int t = 0; t < 4; ++t) {
      if (t < 3) stage_chunk(xb, smem, wave, lane, t + 1);
      const char* xbuf = smem + XT_OFF + jg * 16384 + (t & 1) * 8192;
      const int jbase = jg * 256 + t * 64;
#pragma unroll
      for (int kk = 0; kk < 2; ++kk) {
        const int jb = jbase + kk * 32 + koff;
        float pj[8], ej[8];
        *(float4*)&pj[0] = *(const float4*)&phs[jb];
        *(float4*)&pj[4] = *(const float4*)&phs[jb + 4];
        *(float4*)&ej[0] = *(const float4*)&ehs[jb];
        *(float4*)&ej[4] = *(const float4*)&ehs[jb + 4];
        short8 af[4];
#pragma unroll
        for (int mt = 0; mt < 4; ++mt) {
          unsigned au[4];
#pragma unroll
          for (int pp = 0; pp < 4; ++pp) {
            float dpa = pi_[mt] - pj[2 * pp],     dea = ei_[mt] - ej[2 * pp];
            float dpb = pi_[mt] - pj[2 * pp + 1], deb = ei_[mt] - ej[2 * pp + 1];
            float fa = exp2_fast(-(dpa * dpa + dea * dea));
            float fb = exp2_fast(-(dpb * dpb + deb * deb));
            au[pp] = pack2bf(fa, fb);
          }
          __builtin_memcpy(&af[mt], au, 16);
        }
        const int jc = kk * 32 + koff;
#pragma unroll
        for (int cs = 0; cs < 4; ++cs) {
          const int ch = cs * 16 + c0;
          const int boff = (ch * 128 + jc * 2) ^ ((ch & 7) << 4);
          short8 bf = *(const short8*)(xbuf + boff);
#pragma unroll
          for (int mt = 0; mt < 4; ++mt)
            acc[mt][cs] = __builtin_amdgcn_mfma_f32_16x16x32_bf16(af[mt], bf,
                                                                 acc[mt][cs], 0, 0, 0);
        }
      }
      __syncthreads();
    }

    // ---- J=8 -> 1 reduction, lane-linear slots (conflict-free b128) ----
    char* xt = smem + XT_OFF;
    if (jg >= 4) {
      float* sp = (float*)(xt + ((jg - 4) * 2 + rh) * 16384);
#pragma unroll
      for (int mt = 0; mt < 4; ++mt)
#pragma unroll
        for (int cs = 0; cs < 4; ++cs)
          *(f32x4*)&sp[((mt * 4 + cs) * 64 + lane) * 4] = acc[mt][cs];
    }
    __syncthreads();
    if (jg < 4) {
      const float* sp = (const float*)(xt + (jg * 2 + rh) * 16384);
#pragma unroll
      for (int mt = 0; mt < 4; ++mt)
#pragma unroll
        for (int cs = 0; cs < 4; ++cs)
          acc[mt][cs] += *(const f32x4*)&sp[((mt * 4 + cs) * 64 + lane) * 4];
    }
    __syncthreads();
    if (jg >= 1 && jg < 4) {
      float* sp = (float*)(xt + ((jg - 1) * 2 + rh) * 16384);
#pragma unroll
      for (int mt = 0; mt < 4; ++mt)
#pragma unroll
        for (int cs = 0; cs < 4; ++cs)
          *(f32x4*)&sp[((mt * 4 + cs) * 64 + lane) * 4] = acc[mt][cs];
    }
    __syncthreads();
    if (jg == 0) {
#pragma unroll
      for (int k = 0; k < 3; ++k) {
        const float* sp = (const float*)(xt + (k * 2 + rh) * 16384);
#pragma unroll
        for (int mt = 0; mt < 4; ++mt)
#pragma unroll
          for (int cs = 0; cs < 4; ++cs)
            acc[mt][cs] += *(const f32x4*)&sp[((mt * 4 + cs) * 64 + lane) * 4];
      }
    }
    __syncthreads();  // slots dead; cat/out region may be written

    // ---- cat tile: cols 0..63 = x (L2 restage), 64..127 = s ----
    short* cat = (short*)(smem + XT_OFF);                    // [128][CAT_PITCH]
    short* out_t = (short*)(smem + XT_OFF + 128 * CAT_PITCH * 2);  // [64][CAT_PITCH]
    if (jg == 0) {
#pragma unroll
      for (int mt = 0; mt < 4; ++mt)
#pragma unroll
        for (int cs = 0; cs < 4; ++cs)
#pragma unroll
          for (int r = 0; r < 4; ++r) {
            const int irow = rh * 64 + mt * 16 + hh * 4 + r;  // D: row=(lane>>4)*4+r
            cat[irow * CAT_PITCH + 64 + cs * 16 + c0] = f2bfbits(acc[mt][cs][r]);
          }
    }
    {
      const int cch = tid & 63, rp = tid >> 6;
      short8 v = *(const short8*)&xb[(size_t)cch * NN + i0 + rp * 8];
#pragma unroll
      for (int q = 0; q < 8; ++q) cat[(rp * 8 + q) * CAT_PITCH + cch] = v[q];
    }
    __syncthreads();

    // ---- epilogue: out[o][i] = relu(Wcat.cat + b) + Wr.x + br ----
    {
      const int it = wave & 7;   // i-tile (16 rows)
      const int oh = wave >> 3;  // o-half (32 outputs)
      const int irl = it * 16 + c0;
      short8 bfx[4];
#pragma unroll
      for (int ks = 0; ks < 4; ++ks)
        bfx[ks] = *(const short8*)&cat[irl * CAT_PITCH + ks * 32 + koff];
#pragma unroll
      for (int osl = 0; osl < 2; ++osl) {
        const int os = oh * 2 + osl;
        f32x4 a1 = (f32x4){0.f, 0.f, 0.f, 0.f};
        f32x4 a2 = (f32x4){0.f, 0.f, 0.f, 0.f};
#pragma unroll
        for (int ks = 0; ks < 4; ++ks) {
          short8 whi = *(const short8*)&wcat[(size_t)(((os * 4 + ks) * 64) + lane) * 8];
          short8 wlo = *(const short8*)&wcat[8192 + (size_t)(((os * 4 + ks) * 64) + lane) * 8];
          a1 = __builtin_amdgcn_mfma_f32_16x16x32_bf16(whi, bfx[ks], a1, 0, 0, 0);
          a1 = __builtin_amdgcn_mfma_f32_16x16x32_bf16(wlo, bfx[ks], a1, 0, 0, 0);
        }
#pragma unroll
        for (int ks = 0; ks < 2; ++ks) {
          short8 rhi = *(const short8*)&wrb[(size_t)(((os * 2 + ks) * 64) + lane) * 8];
          short8 rlo = *(const short8*)&wrb[4096 + (size_t)(((os * 2 + ks) * 64) + lane) * 8];
          a2 = __builtin_amdgcn_mfma_f32_16x16x32_bf16(rhi, bfx[ks], a2, 0, 0, 0);
          a2 = __builtin_amdgcn_mfma_f32_16x16x32_bf16(rlo, bfx[ks], a2, 0, 0, 0);
        }
#pragma unroll
        for (int r = 0; r < 4; ++r) {
          const int o = os * 16 + hh * 4 + r;
          float v = fmaxf(a1[r] + bias[o], 0.f) + a2[r] + brs[o];
          out_t[o * CAT_PITCH + it * 16 + c0] = f2bfbits(v);
        }
      }
    }
    __syncthreads();

    // coalesced out copy
    {
      const int o = tid >> 4, part = tid & 15;
      short8 v = *(const short8*)&out_t[o * CAT_PITCH + part * 8];
      *(short8*)&xout[(size_t)b * 64 * NN + (size_t)o * NN + i0 + part * 8] = v;
    }
    grid_barrier(p.bar, nb);
  }

  // ---------------- phase 5: final pooled FC ----------------
  if (iblk == 0) {
    const short* xb = p.xA + (size_t)b * 64 * NN;
    float acc = 0.f;
    for (int f = tid * 8; f < 64 * NN; f += 1024 * 8) {
      short8 v = *(const short8*)&xb[f];
      const float w = p.fcW[f >> 11];
      float ss = 0.f;
#pragma unroll
      for (int e8 = 0; e8 < 8; ++e8) ss += bfbits2f(v[e8]);
      acc += w * ss;
    }
    float* fs = (float*)(smem + XT_OFF);
    fs[tid] = acc;
    __syncthreads();
    for (int off = 512; off > 0; off >>= 1) {
      if (tid < off) fs[tid] += fs[tid + off];
      __syncthreads();
    }
    if (tid == 0) p.out[b] = fs[0] * (1.f / NN) + p.fcb[0];
  }
}

extern "C" void kernel_launch(void* const* d_in, const int* in_sizes, int n_in,
                              void* d_out, int out_size, void* d_ws, size_t ws_size,
                              hipStream_t stream) {
  Params p;
  p.e = (const float*)d_in[0];
  p.phi = (const float*)d_in[1];
  p.eta = (const float*)d_in[2];
  p.W0 = (const float*)d_in[3];  p.B0 = (const float*)d_in[4];
  p.R0 = (const float*)d_in[5];  p.Q0 = (const float*)d_in[6];
  p.W1 = (const float*)d_in[7];  p.B1 = (const float*)d_in[8];
  p.R1 = (const float*)d_in[9];  p.Q1 = (const float*)d_in[10];
  p.W2 = (const float*)d_in[11]; p.B2 = (const float*)d_in[12];
  p.R2 = (const float*)d_in[13]; p.Q2 = (const float*)d_in[14];
  p.W3 = (const float*)d_in[15]; p.B3 = (const float*)d_in[16];
  p.R3 = (const float*)d_in[17]; p.Q3 = (const float*)d_in[18];
  p.fcW = (const float*)d_in[19];
  p.fcb = (const float*)d_in[20];
  p.out = (float*)d_out;

  const size_t XSZ = (size_t)NB * 64 * NN;          // elements per buffer
  p.xA = (short*)d_ws;                              // [0, 4MB)
  p.xB = p.xA + XSZ;                                // [4MB, 8MB)
  p.blob = p.xB + XSZ;                              // [8MB, +200704B)
  p.bar = (unsigned*)((char*)d_ws + (8u << 20) + (256u << 10));  // 8MB+256KB

  hipMemsetAsync(p.bar, 0, 256, stream);
  fused_kernel<<<256, 1024, 0, stream>>>(p);
}

// Round 8
// 237.900 us; speedup vs baseline: 2.2470x; 2.2470x over previous
//
#include <hip/hip_runtime.h>
#include <hip/hip_bf16.h>

#define NN 2048
#define NB 16
#define CAT_PITCH 136    // shorts per cat/out row (272 B == 68 words == 4 mod 32)
#define XT_OFF 16384     // byte offset of per-wave chunk buffers
#define SMEM_BYTES 147456

typedef __attribute__((ext_vector_type(8))) short short8;
typedef __attribute__((ext_vector_type(4))) float f32x4;

static __device__ __forceinline__ float bfbits2f(short s) {
  unsigned int u = ((unsigned int)(unsigned short)s) << 16;
  float f; __builtin_memcpy(&f, &u, 4); return f;
}
static __device__ __forceinline__ short f2bfbits(float f) {
  __hip_bfloat16 h = __float2bfloat16(f);
  unsigned short us; __builtin_memcpy(&us, &h, 2); return (short)us;
}
static __device__ __forceinline__ float exp2_fast(float x) {
#if __has_builtin(__builtin_amdgcn_exp2f)
  return __builtin_amdgcn_exp2f(x);
#else
  return exp2f(x);
#endif
}
// pack two f32 -> two bf16 (round-half-up) in one v_perm
static __device__ __forceinline__ unsigned pack2bf(float f0, float f1) {
  unsigned u0, u1;
  __builtin_memcpy(&u0, &f0, 4);
  __builtin_memcpy(&u1, &f1, 4);
  return __builtin_amdgcn_perm(u1 + 0x8000u, u0 + 0x8000u, 0x07060302u);
}
// async global->LDS, 16B per lane, wave-uniform LDS base + lane*16
static __device__ __forceinline__ void gload_lds16(const void* g, void* l) {
  __builtin_amdgcn_global_load_lds(
      (const __attribute__((address_space(1))) unsigned int*)g,
      (__attribute__((address_space(3))) unsigned int*)l, 16, 0, 0);
}

// ---------------------------------------------------------------------------
// bn + weight-prep merged. grid (16, 65):
//   y<64: batchnorm channel y of batch x -> x0 (ch 3..63 zeroed)
//   y==64 && x<4: pack layer-x weights into MFMA A-frag order (hi+lo bf16)
// ---------------------------------------------------------------------------
__global__ __launch_bounds__(256) void bnprep_kernel(
    const float* __restrict__ e, const float* __restrict__ phi,
    const float* __restrict__ eta, __hip_bfloat16* __restrict__ x0,
    const float* __restrict__ W0, const float* __restrict__ W1,
    const float* __restrict__ W2, const float* __restrict__ W3,
    const float* __restrict__ R0, const float* __restrict__ R1,
    const float* __restrict__ R2, const float* __restrict__ R3,
    short* __restrict__ blob) {
  const int t = threadIdx.x;
  if (blockIdx.y == 64) {
    const int layer = blockIdx.x;
    if (layer >= 4) return;
    const float* W = layer == 0 ? W0 : layer == 1 ? W1 : layer == 2 ? W2 : W3;
    const float* R = layer == 0 ? R0 : layer == 1 ? R1 : layer == 2 ? R2 : R3;
    const int CIN = layer == 0 ? 3 : 64;
    short* base = blob + layer * 24576;
    for (int f = t; f < 8192; f += 256) {
      int e8 = f & 7, ln = (f >> 3) & 63, ks = (f >> 9) & 3, os = f >> 11;
      int o = os * 16 + (ln & 15);
      int k = ks * 32 + (ln >> 4) * 8 + e8;
      float v = 0.f;
      if (k < 64) { if (k < CIN) v = W[o * 2 * CIN + k]; }
      else { int c = k - 64; if (c < CIN) v = W[o * 2 * CIN + CIN + c]; }
      short hi = f2bfbits(v);
      base[f] = hi;
      base[8192 + f] = f2bfbits(v - bfbits2f(hi));
    }
    for (int f = t; f < 4096; f += 256) {
      int e8 = f & 7, ln = (f >> 3) & 63, ks = (f >> 9) & 1, os = f >> 10;
      int o = os * 16 + (ln & 15);
      int k = ks * 32 + (ln >> 4) * 8 + e8;
      float v = (k < CIN) ? R[o * CIN + k] : 0.f;
      short hi = f2bfbits(v);
      base[16384 + f] = hi;
      base[20480 + f] = f2bfbits(v - bfbits2f(hi));
    }
    return;
  }
  const int b = blockIdx.x;
  const int c = blockIdx.y;
  __hip_bfloat16* out = x0 + ((size_t)b * 64 + c) * NN;
  if (c >= 3) {
    short8 z = {0, 0, 0, 0, 0, 0, 0, 0};
    for (int idx = t * 8; idx < NN; idx += 256 * 8) *(short8*)&out[idx] = z;
    return;
  }
  const float* src = (c == 0 ? e : (c == 1 ? eta : phi)) + (size_t)b * NN;
  float sum = 0.f, sq = 0.f;
  for (int idx = t * 4; idx < NN; idx += 256 * 4) {
    float4 v = *(const float4*)&src[idx];
    sum += v.x + v.y + v.z + v.w;
    sq += v.x * v.x + v.y * v.y + v.z * v.z + v.w * v.w;
  }
  __shared__ float rs[256], rq[256];
  rs[t] = sum; rq[t] = sq;
  __syncthreads();
  for (int off = 128; off > 0; off >>= 1) {
    if (t < off) { rs[t] += rs[t + off]; rq[t] += rq[t + off]; }
    __syncthreads();
  }
  const float m = rs[0] * (1.f / NN);
  const float var = fmaxf(rq[0] * (1.f / NN) - m * m, 0.f);
  const float rinv = 1.f / (sqrtf(var) + 1e-5f);
  for (int idx = t * 4; idx < NN; idx += 256 * 4) {
    float4 v = *(const float4*)&src[idx];
    out[idx + 0] = __float2bfloat16((v.x - m) * rinv);
    out[idx + 1] = __float2bfloat16((v.y - m) * rinv);
    out[idx + 2] = __float2bfloat16((v.z - m) * rinv);
    out[idx + 3] = __float2bfloat16((v.w - m) * rinv);
  }
}

// ---------------------------------------------------------------------------
// Fused layer, barrier-free j-loop. 16 waves = (rh:2 row-halves) x (jg:8
// j-groups of 256). Each wave double-buffers PRIVATE 4 KB chunks (16ch x 32j
// granules, XOR-swizzled via pre-swizzled global source), self-paced with
// counted s_waitcnt vmcnt(4) -- no __syncthreads in the j-loop.
// ---------------------------------------------------------------------------
__global__ __launch_bounds__(1024, 4) void layer_kernel(
    const float* __restrict__ phi, const float* __restrict__ eta,
    const __hip_bfloat16* __restrict__ x, const short* __restrict__ wcat,
    const short* __restrict__ wrb, const float* __restrict__ bias,
    const float* __restrict__ brs, __hip_bfloat16* __restrict__ xo) {
  const int bid = blockIdx.x;
  const int sid = (bid & 7) * 32 + (bid >> 3);  // XCD-local: 2 batches per XCD
  const int b = sid >> 4;
  const int i0 = (sid & 15) * 128;
  const int tid = threadIdx.x;
  const int wave = tid >> 6;
  const int lane = tid & 63;
  const int c0 = lane & 15;
  const int hh = lane >> 4;
  const int koff = hh * 8;
  const int rh = wave & 1;      // row half (64 rows)
  const int jg = wave >> 1;     // j-group (256 j)

  __shared__ __align__(16) char smem[SMEM_BYTES];
  float* phs = (float*)smem;          // [2048]
  float* ehs = phs + NN;              // [2048]

  const float SC = 1.20112240872f;    // sqrt(log2 e): exp2(-(SC*d)^2)=exp(-d^2)
  {
    const float* pb = phi + (size_t)b * NN;
    const float* eb = eta + (size_t)b * NN;
    for (int idx = tid; idx < NN; idx += 1024) {
      phs[idx] = pb[idx] * SC;
      ehs[idx] = eb[idx] * SC;
    }
  }
  const short* xb = (const short*)(x + (size_t)b * 64 * NN);

  // stager inverse-swizzle lane map (write side of addr^((ch&7)<<4))
  const int d4 = lane & 1, d5 = (lane >> 1) & 1, d6 = (lane >> 2) & 1;
  const int d7 = (lane >> 3) & 1, d8 = (lane >> 4) & 1, d9 = (lane >> 5) & 1;
  const int ch_l = (d9 << 3) | (d8 << 2) | (d7 << 1) | (d6 ^ d8);
  const int jb8 = ((d5 ^ d7) << 1) | (d4 ^ d6 ^ d8);
  char* wbuf = smem + XT_OFF + wave * 8192;

#define STAGE(tt)                                                             \
  {                                                                           \
    const int _t = (tt);                                                      \
    _Pragma("unroll")                                                         \
    for (int gsl = 0; gsl < 4; ++gsl)                                         \
      gload_lds16(xb + (size_t)(gsl * 16 + ch_l) * NN + jg * 256 + _t * 32 +  \
                      jb8 * 8,                                                \
                  wbuf + (_t & 1) * 4096 + gsl * 1024);                       \
  }

  STAGE(0);        // drained by the barrier below
  __syncthreads(); // phs/ehs visible to all

  float pi_[4], ei_[4];
#pragma unroll
  for (int mt = 0; mt < 4; ++mt) {
    const int row = i0 + rh * 64 + mt * 16 + c0;
    pi_[mt] = phs[row];
    ei_[mt] = ehs[row];
  }

  f32x4 acc[4][4];
#pragma unroll
  for (int mt = 0; mt < 4; ++mt)
#pragma unroll
    for (int cs = 0; cs < 4; ++cs) acc[mt][cs] = (f32x4){0.f, 0.f, 0.f, 0.f};

#define COMPUTE(tt)                                                           \
  {                                                                           \
    const int _t = (tt);                                                      \
    const char* xbuf = wbuf + (_t & 1) * 4096;                                \
    const int jb = jg * 256 + _t * 32 + koff;                                 \
    float pj[8], ej[8];                                                       \
    *(float4*)&pj[0] = *(const float4*)&phs[jb];                              \
    *(float4*)&pj[4] = *(const float4*)&phs[jb + 4];                          \
    *(float4*)&ej[0] = *(const float4*)&ehs[jb];                              \
    *(float4*)&ej[4] = *(const float4*)&ehs[jb + 4];                          \
    short8 af[4];                                                             \
    _Pragma("unroll")                                                         \
    for (int mt = 0; mt < 4; ++mt) {                                          \
      unsigned au[4];                                                         \
      _Pragma("unroll")                                                       \
      for (int pp = 0; pp < 4; ++pp) {                                        \
        float dpa = pi_[mt] - pj[2 * pp],     dea = ei_[mt] - ej[2 * pp];     \
        float dpb = pi_[mt] - pj[2 * pp + 1], deb = ei_[mt] - ej[2 * pp + 1]; \
        float fa = exp2_fast(-(dpa * dpa + dea * dea));                       \
        float fb = exp2_fast(-(dpb * dpb + deb * deb));                       \
        au[pp] = pack2bf(fa, fb);                                             \
      }                                                                       \
      __builtin_memcpy(&af[mt], au, 16);                                      \
    }                                                                         \
    _Pragma("unroll")                                                         \
    for (int cs = 0; cs < 4; ++cs) {                                          \
      short8 bf = *(const short8*)(xbuf + cs * 1024 +                         \
                                   ((c0 * 64 + koff * 2) ^ ((c0 & 7) << 4))); \
      _Pragma("unroll")                                                       \
      for (int mt = 0; mt < 4; ++mt)                                          \
        acc[mt][cs] = __builtin_amdgcn_mfma_f32_16x16x32_bf16(af[mt], bf,     \
                                                          acc[mt][cs], 0, 0, 0); \
    }                                                                         \
  }

#pragma unroll 1
  for (int t = 0; t < 7; ++t) {
    STAGE(t + 1);
    __builtin_amdgcn_sched_barrier(0);
    asm volatile("s_waitcnt vmcnt(4)" ::: "memory");
    __builtin_amdgcn_sched_barrier(0);
    COMPUTE(t);
    __builtin_amdgcn_sched_barrier(0);
  }
  asm volatile("s_waitcnt vmcnt(0)" ::: "memory");
  __builtin_amdgcn_sched_barrier(0);
  COMPUTE(7);
  __syncthreads();  // all waves done with j-loop; buffers become slots

  // ---- J=8 -> 1 reduction, lane-linear f32 slots (conflict-free b128) ----
  char* xt = smem + XT_OFF;
  if (jg >= 4) {
    float* sp = (float*)(xt + ((jg - 4) * 2 + rh) * 16384);
#pragma unroll
    for (int mt = 0; mt < 4; ++mt)
#pragma unroll
      for (int cs = 0; cs < 4; ++cs)
        *(f32x4*)&sp[((mt * 4 + cs) * 64 + lane) * 4] = acc[mt][cs];
  }
  __syncthreads();
  if (jg < 4) {
    const float* sp = (const float*)(xt + (jg * 2 + rh) * 16384);
#pragma unroll
    for (int mt = 0; mt < 4; ++mt)
#pragma unroll
      for (int cs = 0; cs < 4; ++cs)
        acc[mt][cs] += *(const f32x4*)&sp[((mt * 4 + cs) * 64 + lane) * 4];
  }
  __syncthreads();
  if (jg >= 1 && jg < 4) {
    float* sp = (float*)(xt + ((jg - 1) * 2 + rh) * 16384);
#pragma unroll
    for (int mt = 0; mt < 4; ++mt)
#pragma unroll
      for (int cs = 0; cs < 4; ++cs)
        *(f32x4*)&sp[((mt * 4 + cs) * 64 + lane) * 4] = acc[mt][cs];
  }
  __syncthreads();
  if (jg == 0) {
#pragma unroll
    for (int k = 0; k < 3; ++k) {
      const float* sp = (const float*)(xt + (k * 2 + rh) * 16384);
#pragma unroll
      for (int mt = 0; mt < 4; ++mt)
#pragma unroll
        for (int cs = 0; cs < 4; ++cs)
          acc[mt][cs] += *(const f32x4*)&sp[((mt * 4 + cs) * 64 + lane) * 4];
    }
  }
  __syncthreads();  // slots dead; cat/out region may be written

  // ---- cat tile: cols 0..63 = x (L2 restage), 64..127 = s ----
  short* cat = (short*)(smem + XT_OFF);                          // [128][136]
  short* out_t = (short*)(smem + XT_OFF + 128 * CAT_PITCH * 2);  // [64][136]
  if (jg == 0) {
#pragma unroll
    for (int mt = 0; mt < 4; ++mt)
#pragma unroll
      for (int cs = 0; cs < 4; ++cs)
#pragma unroll
        for (int r = 0; r < 4; ++r) {
          const int irow = rh * 64 + mt * 16 + hh * 4 + r;  // D: row=(lane>>4)*4+r
          cat[irow * CAT_PITCH + 64 + cs * 16 + c0] = f2bfbits(acc[mt][cs][r]);
        }
  }
  {
    const int cch = tid & 63, rp = tid >> 6;
    short8 v = *(const short8*)&xb[(size_t)cch * NN + i0 + rp * 8];
#pragma unroll
    for (int q = 0; q < 8; ++q) cat[(rp * 8 + q) * CAT_PITCH + cch] = v[q];
  }
  __syncthreads();

  // ---- epilogue: out[o][i] = relu(Wcat.cat + b) + Wr.x + br (hi+lo wts) ----
  {
    const int it = wave & 7;   // i-tile (16 rows)
    const int oh = wave >> 3;  // o-half (32 outputs)
    const int irl = it * 16 + c0;
    short8 bfx[4];
#pragma unroll
    for (int ks = 0; ks < 4; ++ks)
      bfx[ks] = *(const short8*)&cat[irl * CAT_PITCH + ks * 32 + koff];
#pragma unroll
    for (int osl = 0; osl < 2; ++osl) {
      const int os = oh * 2 + osl;
      f32x4 a1 = (f32x4){0.f, 0.f, 0.f, 0.f};
      f32x4 a2 = (f32x4){0.f, 0.f, 0.f, 0.f};
#pragma unroll
      for (int ks = 0; ks < 4; ++ks) {
        short8 whi = *(const short8*)&wcat[(size_t)(((os * 4 + ks) * 64) + lane) * 8];
        short8 wlo = *(const short8*)&wcat[8192 + (size_t)(((os * 4 + ks) * 64) + lane) * 8];
        a1 = __builtin_amdgcn_mfma_f32_16x16x32_bf16(whi, bfx[ks], a1, 0, 0, 0);
        a1 = __builtin_amdgcn_mfma_f32_16x16x32_bf16(wlo, bfx[ks], a1, 0, 0, 0);
      }
#pragma unroll
      for (int ks = 0; ks < 2; ++ks) {
        short8 rhi = *(const short8*)&wrb[(size_t)(((os * 2 + ks) * 64) + lane) * 8];
        short8 rlo = *(const short8*)&wrb[4096 + (size_t)(((os * 2 + ks) * 64) + lane) * 8];
        a2 = __builtin_amdgcn_mfma_f32_16x16x32_bf16(rhi, bfx[ks], a2, 0, 0, 0);
        a2 = __builtin_amdgcn_mfma_f32_16x16x32_bf16(rlo, bfx[ks], a2, 0, 0, 0);
      }
#pragma unroll
      for (int r = 0; r < 4; ++r) {
        const int o = os * 16 + hh * 4 + r;
        float v = fmaxf(a1[r] + bias[o], 0.f) + a2[r] + brs[o];
        out_t[o * CAT_PITCH + it * 16 + c0] = f2bfbits(v);
      }
    }
  }
  __syncthreads();

  // coalesced out copy
  {
    const int o = tid >> 4, part = tid & 15;
    short8 v = *(const short8*)&out_t[o * CAT_PITCH + part * 8];
    *(short8*)((short*)xo + (size_t)b * 64 * NN + (size_t)o * NN + i0 + part * 8) = v;
  }
#undef STAGE
#undef COMPUTE
}

// ---------------------------------------------------------------------------
// Final: out[b] = (1/NN) * sum_{c,i} fcW[c]*x[c,i] + fcb
// ---------------------------------------------------------------------------
__global__ __launch_bounds__(256) void final_kernel(
    const __hip_bfloat16* __restrict__ x, const float* __restrict__ fcW,
    const float* __restrict__ fcb, float* __restrict__ out) {
  const int b = blockIdx.x;
  const short* xb = (const short*)(x + (size_t)b * 64 * NN);
  float acc = 0.f;
  for (int f = threadIdx.x * 8; f < 64 * NN; f += 256 * 8) {
    short8 v = *(const short8*)&xb[f];
    const float w = fcW[f >> 11];
    float ss = 0.f;
#pragma unroll
    for (int e8 = 0; e8 < 8; ++e8) ss += bfbits2f(v[e8]);
    acc += w * ss;
  }
  __shared__ float red[256];
  red[threadIdx.x] = acc;
  __syncthreads();
  for (int off = 128; off > 0; off >>= 1) {
    if ((int)threadIdx.x < off) red[threadIdx.x] += red[threadIdx.x + off];
    __syncthreads();
  }
  if (threadIdx.x == 0) out[b] = red[0] * (1.f / NN) + fcb[0];
}

extern "C" void kernel_launch(void* const* d_in, const int* in_sizes, int n_in,
                              void* d_out, int out_size, void* d_ws, size_t ws_size,
                              hipStream_t stream) {
  const float* e   = (const float*)d_in[0];
  const float* phi = (const float*)d_in[1];
  const float* eta = (const float*)d_in[2];
  const float* W[4]  = {(const float*)d_in[3],  (const float*)d_in[7],
                        (const float*)d_in[11], (const float*)d_in[15]};
  const float* bb[4] = {(const float*)d_in[4],  (const float*)d_in[8],
                        (const float*)d_in[12], (const float*)d_in[16]};
  const float* Wr[4] = {(const float*)d_in[5],  (const float*)d_in[9],
                        (const float*)d_in[13], (const float*)d_in[17]};
  const float* br[4] = {(const float*)d_in[6],  (const float*)d_in[10],
                        (const float*)d_in[14], (const float*)d_in[18]};
  const float* fcW = (const float*)d_in[19];
  const float* fcb = (const float*)d_in[20];
  float* outp = (float*)d_out;

  const size_t XSZ = (size_t)NB * 64 * NN;
  __hip_bfloat16* xA = (__hip_bfloat16*)d_ws;  // [0, 4MB)
  __hip_bfloat16* xB = xA + XSZ;               // [4MB, 8MB)
  short* blob = (short*)(xB + XSZ);            // [8MB, 8MB+192KB)

  bnprep_kernel<<<dim3(16, 65), 256, 0, stream>>>(
      e, phi, eta, xA, W[0], W[1], W[2], W[3], Wr[0], Wr[1], Wr[2], Wr[3], blob);

  const __hip_bfloat16* xin = xA;
  __hip_bfloat16* xout = xB;
  for (int l = 0; l < 4; ++l) {
    const short* lb = blob + l * 24576;
    layer_kernel<<<256, 1024, 0, stream>>>(phi, eta, xin, lb, lb + 16384,
                                           bb[l], br[l], xout);
    const __hip_bfloat16* t = xout; xout = (__hip_bfloat16*)xin; xin = t;
  }
  // after 4 layers output is back in xA
  final_kernel<<<NB, 256, 0, stream>>>(xA, fcW, fcb, outp);
}